// Round 1
// 1960.481 us; speedup vs baseline: 1.3589x; 1.3589x over previous
//
#include <hip/hip_runtime.h>
#include <hip/hip_bf16.h>

typedef unsigned long long u64;
typedef __bf16 bf16_t;
typedef __attribute__((ext_vector_type(8))) __bf16 bf16x8;
typedef __attribute__((ext_vector_type(4))) __bf16 bf16x4;
typedef __attribute__((ext_vector_type(4))) float f32x4;

#define NROWS 16384
#define KLAT  768
#define EDIM  256
#define NE    8192
#define ODIM  768

// output element offsets (FLOAT32 elements — d_out is fp32, 16,801,795 elems)
#define OFF_ZQ   0
#define OFF_IND  12582912
#define OFF_LOSS 12599296
#define OFF_EMB  12599297
#define OFF_EAVG 14696449
#define OFF_CSF  16793601
#define OFF_EMIN 16801793
#define OFF_CMT  16801794

// workspace layout (all scratch in d_ws; ~25.76 MB; R6 proved ws_size >= this)
#define W_XN    0u           // f32 xn [16384][256]      (16,777,216 B)
#define W_ESUM  16777216u    // f32 esum [8192][256]     ( 8,388,608 B)
#define W_RMIN  25165824u    // u64 rowmin [16384]
#define W_RZ    25296896u    // f32 rowZ
#define W_RS1   25362432u    // f32 rowS1
#define W_INVZ  25427968u    // f32 invZ
#define W_INDW  25493504u    // i32 ind
#define W_BINS  25559040u    // f32 bins [8192]
#define W_CN    25591808u    // f32 cluster_new
#define W_CSM   25624576u    // f32 cs smoothed
#define W_IDXS  25657344u    // i32 sampled idx
#define W_AP    25690112u    // f32 ap [8192]
#define W_SCAL  25722880u    // f32 scal[4]
#define W_END   25722896u

// ---------------------------------------------------------------------------
// zero-fill fallback (guard path only)
// ---------------------------------------------------------------------------
__global__ __launch_bounds__(256) void zero_out_kernel(float* __restrict__ out, int n)
{
  int i = blockIdx.x * 256 + threadIdx.x;
  if (i < n) out[i] = 0.0f;
}

// ---------------------------------------------------------------------------
// GEMM-in: xn[M][256] = x[M][768] @ W_in[256][768]^T + b_in  (fp32 out)
// ---------------------------------------------------------------------------
__global__ __launch_bounds__(256) void gemm_in_kernel(
    const float* __restrict__ A, const float* __restrict__ B,
    const float* __restrict__ bias, float* __restrict__ C)
{
  __shared__ float As[16][64];
  __shared__ float Bs[16][64];
  const int tid = threadIdx.x;
  const int tx = tid & 15, ty = tid >> 4;
  const int bm = blockIdx.x << 6, bn = blockIdx.y << 6;
  const int lr = tid >> 2, lk = (tid & 3) << 2;
  const size_t aoff = (size_t)(bm + lr) * KLAT;
  const size_t boff = (size_t)(bn + lr) * KLAT;
  float acc[4][4] = {};
  for (int k0 = 0; k0 < KLAT; k0 += 16) {
    __syncthreads();
    float4 av = *(const float4*)(A + aoff + k0 + lk);
    float4 bv = *(const float4*)(B + boff + k0 + lk);
    As[lk + 0][lr] = av.x; As[lk + 1][lr] = av.y; As[lk + 2][lr] = av.z; As[lk + 3][lr] = av.w;
    Bs[lk + 0][lr] = bv.x; Bs[lk + 1][lr] = bv.y; Bs[lk + 2][lr] = bv.z; Bs[lk + 3][lr] = bv.w;
    __syncthreads();
#pragma unroll
    for (int kk = 0; kk < 16; ++kk) {
      float4 a4 = *(const float4*)&As[kk][ty << 2];
      float4 b4 = *(const float4*)&Bs[kk][tx << 2];
      float ar[4] = {a4.x, a4.y, a4.z, a4.w};
      float br[4] = {b4.x, b4.y, b4.z, b4.w};
#pragma unroll
      for (int i = 0; i < 4; ++i)
#pragma unroll
        for (int j = 0; j < 4; ++j)
          acc[i][j] = fmaf(ar[i], br[j], acc[i][j]);
    }
  }
  float4 b4 = *(const float4*)(bias + bn + (tx << 2));
  float bb[4] = {b4.x, b4.y, b4.z, b4.w};
#pragma unroll
  for (int i = 0; i < 4; ++i) {
    const size_t row = (size_t)(bm + (ty << 2) + i);
    float4 o = make_float4(acc[i][0] + bb[0], acc[i][1] + bb[1],
                           acc[i][2] + bb[2], acc[i][3] + bb[3]);
    *(float4*)(C + row * EDIM + bn + (tx << 2)) = o;
  }
}

// ---------------------------------------------------------------------------
// GEMM-out: out[M][768] = embed[ind[M]][256] @ W_out[768][256]^T + b_out
// fp32 stores directly into d_out chunk 0.
// ---------------------------------------------------------------------------
__global__ __launch_bounds__(256) void gemm_out_kernel(
    const float* __restrict__ A, const float* __restrict__ B,
    const float* __restrict__ bias, const int* __restrict__ gather,
    float* __restrict__ C)
{
  __shared__ float As[16][64];
  __shared__ float Bs[16][64];
  const int tid = threadIdx.x;
  const int tx = tid & 15, ty = tid >> 4;
  const int bm = blockIdx.x << 6, bn = blockIdx.y << 6;
  const int lr = tid >> 2, lk = (tid & 3) << 2;
  const size_t arow = (size_t)(gather[bm + lr] & (NE - 1));
  const size_t aoff = arow * EDIM;
  const size_t boff = (size_t)(bn + lr) * EDIM;
  float acc[4][4] = {};
  for (int k0 = 0; k0 < EDIM; k0 += 16) {
    __syncthreads();
    float4 av = *(const float4*)(A + aoff + k0 + lk);
    float4 bv = *(const float4*)(B + boff + k0 + lk);
    As[lk + 0][lr] = av.x; As[lk + 1][lr] = av.y; As[lk + 2][lr] = av.z; As[lk + 3][lr] = av.w;
    Bs[lk + 0][lr] = bv.x; Bs[lk + 1][lr] = bv.y; Bs[lk + 2][lr] = bv.z; Bs[lk + 3][lr] = bv.w;
    __syncthreads();
#pragma unroll
    for (int kk = 0; kk < 16; ++kk) {
      float4 a4 = *(const float4*)&As[kk][ty << 2];
      float4 b4 = *(const float4*)&Bs[kk][tx << 2];
      float ar[4] = {a4.x, a4.y, a4.z, a4.w};
      float br[4] = {b4.x, b4.y, b4.z, b4.w};
#pragma unroll
      for (int i = 0; i < 4; ++i)
#pragma unroll
        for (int j = 0; j < 4; ++j)
          acc[i][j] = fmaf(ar[i], br[j], acc[i][j]);
    }
  }
  float4 b4 = *(const float4*)(bias + bn + (tx << 2));
  float bb[4] = {b4.x, b4.y, b4.z, b4.w};
#pragma unroll
  for (int i = 0; i < 4; ++i) {
    const size_t row = (size_t)(bm + (ty << 2) + i);
    float4 o = make_float4(acc[i][0] + bb[0], acc[i][1] + bb[1],
                           acc[i][2] + bb[2], acc[i][3] + bb[3]);
    *(float4*)(C + row * ODIM + bn + (tx << 2)) = o;
  }
}

// ---------------------------------------------------------------------------
__global__ __launch_bounds__(256) void l2norm_kernel(float* __restrict__ xn)
{
  __shared__ float sb[4];
  const int r = blockIdx.x, t = threadIdx.x;
  float v = xn[(size_t)r * EDIM + t];
  float s = v * v;
#pragma unroll
  for (int off = 32; off >= 1; off >>= 1) s += __shfl_xor(s, off);
  if ((t & 63) == 0) sb[t >> 6] = s;
  __syncthreads();
  float tot = sb[0] + sb[1] + sb[2] + sb[3];
  xn[(size_t)r * EDIM + t] = v / sqrtf(tot);
}

// ---------------------------------------------------------------------------
// Phase 1: 64 rows x 1024 codes per block; fp32 d; per-row argmin/Z/S1.
// key = bits(d+2.0) (d+2 in (0,4) => monotone); (key<<32)|idx, atomicMin.
// KEPT fp32: argmin (embed_ind output) is the only numerically fragile path.
// ---------------------------------------------------------------------------
#define P_CSPAN 1024
__global__ __launch_bounds__(256) void phase1_kernel(
    const float* __restrict__ xn, const float* __restrict__ embed,
    u64* __restrict__ rowmin, float* __restrict__ rowZ, float* __restrict__ rowS1)
{
  __shared__ float xs[64][68];
  __shared__ float es[64][68];
  const int tid = threadIdx.x;
  const int tx = tid & 15, ty = tid >> 4;
  const int bm = blockIdx.x << 6;
  const int cb = blockIdx.y * P_CSPAN;
  const int sr = tid >> 2;
  const int skq = (tid & 3) << 2;
  u64 mkey[4] = {~0ull, ~0ull, ~0ull, ~0ull};
  float Zs[4]  = {0.f, 0.f, 0.f, 0.f};
  float S1s[4] = {0.f, 0.f, 0.f, 0.f};
  for (int cc = 0; cc < P_CSPAN; cc += 64) {
    float acc[4][4] = {};
    for (int k0 = 0; k0 < EDIM; k0 += 64) {
      __syncthreads();
#pragma unroll
      for (int q = 0; q < 4; ++q) {
        int k = skq + (q << 4);
        float4 xv = *(const float4*)(xn + (size_t)(bm + sr) * EDIM + k0 + k);
        xs[k + 0][sr] = xv.x; xs[k + 1][sr] = xv.y; xs[k + 2][sr] = xv.z; xs[k + 3][sr] = xv.w;
        float4 ev = *(const float4*)(embed + (size_t)(cb + cc + sr) * EDIM + k0 + k);
        es[k + 0][sr] = ev.x; es[k + 1][sr] = ev.y; es[k + 2][sr] = ev.z; es[k + 3][sr] = ev.w;
      }
      __syncthreads();
#pragma unroll 16
      for (int k = 0; k < 64; ++k) {
        float4 a4 = *(const float4*)&xs[k][ty << 2];
        float4 b4 = *(const float4*)&es[k][tx << 2];
        float ar[4] = {a4.x, a4.y, a4.z, a4.w};
        float br[4] = {b4.x, b4.y, b4.z, b4.w};
#pragma unroll
        for (int i = 0; i < 4; ++i)
#pragma unroll
          for (int j = 0; j < 4; ++j)
            acc[i][j] = fmaf(ar[i], br[j], acc[i][j]);
      }
    }
#pragma unroll
    for (int i = 0; i < 4; ++i) {
#pragma unroll
      for (int j = 0; j < 4; ++j) {
        float d = acc[i][j];
        float l = 10.f * d;
        float e = __expf(l);
        Zs[i]  += e;
        S1s[i] += l * e;
        u64 key = ((u64)__float_as_uint(d + 2.0f) << 32)
                | (unsigned)(cb + cc + (tx << 2) + j);
        if (key < mkey[i]) mkey[i] = key;
      }
    }
  }
#pragma unroll
  for (int i = 0; i < 4; ++i) {
#pragma unroll
    for (int off = 1; off < 16; off <<= 1) {
      u64 ok = __shfl_xor(mkey[i], off);
      if (ok < mkey[i]) mkey[i] = ok;
      Zs[i]  += __shfl_xor(Zs[i], off);
      S1s[i] += __shfl_xor(S1s[i], off);
    }
    if (tx == 0) {
      int row = bm + (ty << 2) + i;
      atomicMin(rowmin + row, mkey[i]);
      atomicAdd(rowZ + row, Zs[i]);
      atomicAdd(rowS1 + row, S1s[i]);
    }
  }
}

// ---------------------------------------------------------------------------
// Phase 2 (MFMA): ap[c] += exp(10*d~) * invZ[row], d~ via bf16x3 split MFMA.
// d~ error ~1e-7..1e-6 (hi/lo bf16 split: residual <= 2^-18|x|; lo*lo term
// dropped <= 2^-18 relative) -> exp(10 d~) relative error ~1e-5: far inside
// tolerance for the entropy outputs. Argmin untouched (phase1 fp32).
// Tile 128x128, BK=64, 4 waves (2x2), each wave 64x64 = 4x4 frags of 16x16x32.
// LDS rows padded to 72 bf16 (144B = 36 dwords = 4 banks): staging writes and
// ds_read_b128 frag reads are <=2-way (free, m136).
// ---------------------------------------------------------------------------
__global__ __launch_bounds__(256) void phase2_mfma_kernel(
    const float* __restrict__ xn, const float* __restrict__ embed,
    const float* __restrict__ invZ, float* __restrict__ ap)
{
  __shared__ bf16_t Ah[128][72];
  __shared__ bf16_t Al[128][72];
  __shared__ bf16_t Bh[128][72];
  __shared__ bf16_t Bl[128][72];
  const int tid  = threadIdx.x;
  const int lane = tid & 63;
  const int wave = tid >> 6;           // 0..3
  const int wm = wave >> 1;            // wave row  (0..1) -> 64 rows each
  const int wn = wave & 1;             // wave col  (0..1) -> 64 cols each
  const int row_m = blockIdx.x << 7;   // xn row base
  const int col_n = blockIdx.y << 7;   // embed row (code) base
  const int sr = tid >> 4;             // staging: row-in-pass 0..15
  const int sk = (tid & 15) << 2;      // staging: fp32 k offset 0..60

  f32x4 acc[4][4] = {};

  for (int k0 = 0; k0 < EDIM; k0 += 64) {
    __syncthreads();
#pragma unroll
    for (int p = 0; p < 8; ++p) {
      const int r = (p << 4) + sr;
      float4 v = *(const float4*)(xn + (size_t)(row_m + r) * EDIM + k0 + sk);
      bf16_t h0 = (bf16_t)v.x, h1 = (bf16_t)v.y, h2 = (bf16_t)v.z, h3 = (bf16_t)v.w;
      bf16_t l0 = (bf16_t)(v.x - (float)h0), l1 = (bf16_t)(v.y - (float)h1);
      bf16_t l2 = (bf16_t)(v.z - (float)h2), l3 = (bf16_t)(v.w - (float)h3);
      bf16x4 hv = {h0, h1, h2, h3};
      bf16x4 lv = {l0, l1, l2, l3};
      *(bf16x4*)&Ah[r][sk] = hv;
      *(bf16x4*)&Al[r][sk] = lv;
    }
#pragma unroll
    for (int p = 0; p < 8; ++p) {
      const int r = (p << 4) + sr;
      float4 v = *(const float4*)(embed + (size_t)(col_n + r) * EDIM + k0 + sk);
      bf16_t h0 = (bf16_t)v.x, h1 = (bf16_t)v.y, h2 = (bf16_t)v.z, h3 = (bf16_t)v.w;
      bf16_t l0 = (bf16_t)(v.x - (float)h0), l1 = (bf16_t)(v.y - (float)h1);
      bf16_t l2 = (bf16_t)(v.z - (float)h2), l3 = (bf16_t)(v.w - (float)h3);
      bf16x4 hv = {h0, h1, h2, h3};
      bf16x4 lv = {l0, l1, l2, l3};
      *(bf16x4*)&Bh[r][sk] = hv;
      *(bf16x4*)&Bl[r][sk] = lv;
    }
    __syncthreads();
#pragma unroll
    for (int kk = 0; kk < 2; ++kk) {
      const int kf = (kk << 5) + ((lane >> 4) << 3);   // k-offset of this lane's 8 bf16
      bf16x8 ah[4], al[4], bh[4], bl[4];
#pragma unroll
      for (int m = 0; m < 4; ++m) {
        const int r = (wm << 6) + (m << 4) + (lane & 15);
        ah[m] = *(const bf16x8*)&Ah[r][kf];
        al[m] = *(const bf16x8*)&Al[r][kf];
      }
#pragma unroll
      for (int n = 0; n < 4; ++n) {
        const int c = (wn << 6) + (n << 4) + (lane & 15);
        bh[n] = *(const bf16x8*)&Bh[c][kf];
        bl[n] = *(const bf16x8*)&Bl[c][kf];
      }
#pragma unroll
      for (int m = 0; m < 4; ++m)
#pragma unroll
        for (int n = 0; n < 4; ++n) {
          acc[m][n] = __builtin_amdgcn_mfma_f32_16x16x32_bf16(ah[m], bh[n], acc[m][n], 0, 0, 0);
          acc[m][n] = __builtin_amdgcn_mfma_f32_16x16x32_bf16(ah[m], bl[n], acc[m][n], 0, 0, 0);
          acc[m][n] = __builtin_amdgcn_mfma_f32_16x16x32_bf16(al[m], bh[n], acc[m][n], 0, 0, 0);
        }
    }
  }

  // Epilogue: C/D layout (m89): col = lane&15, row = (lane>>4)*4 + reg.
  float iz[4][4];
#pragma unroll
  for (int m = 0; m < 4; ++m)
#pragma unroll
    for (int q = 0; q < 4; ++q)
      iz[m][q] = invZ[row_m + (wm << 6) + (m << 4) + ((lane >> 4) << 2) + q];
#pragma unroll
  for (int n = 0; n < 4; ++n) {
    float s = 0.f;
#pragma unroll
    for (int m = 0; m < 4; ++m)
#pragma unroll
      for (int q = 0; q < 4; ++q)
        s += __expf(10.f * acc[m][n][q]) * iz[m][q];
    s += __shfl_xor(s, 16);          // reduce over the 4 row-groups
    s += __shfl_xor(s, 32);
    if (lane < 16)
      atomicAdd(ap + col_n + (wn << 6) + (n << 4) + lane, s);
  }
}

// ---------------------------------------------------------------------------
__global__ __launch_bounds__(256) void row_finalize_kernel(
    const u64* __restrict__ rowmin, const float* __restrict__ rowZ,
    const float* __restrict__ rowS1, float* __restrict__ invZ,
    int* __restrict__ indw, float* __restrict__ bins,
    float* __restrict__ scal, float* __restrict__ out)
{
  __shared__ float sb[4];
  const int r = blockIdx.x * 256 + threadIdx.x;
  const int t = threadIdx.x;
  int ind = ((int)(unsigned)(rowmin[r] & 0xFFFFFFFFull)) & (NE - 1);
  indw[r] = ind;
  out[OFF_IND + r] = (float)ind;
  atomicAdd(bins + ind, 1.0f);
  float Z = rowZ[r], S1 = rowS1[r];
  invZ[r] = 1.0f / Z;
  float ent = logf(Z) - S1 / Z;
#pragma unroll
  for (int off = 32; off >= 1; off >>= 1) ent += __shfl_xor(ent, off);
  if ((t & 63) == 0) sb[t >> 6] = ent;
  __syncthreads();
  if (t == 0) atomicAdd(scal + 1, sb[0] + sb[1] + sb[2] + sb[3]);
}

// ---------------------------------------------------------------------------
__global__ __launch_bounds__(256) void scatter_commit_kernel(
    const float* __restrict__ xn, const float* __restrict__ embed,
    const int* __restrict__ indw, float* __restrict__ esum, float* __restrict__ scal)
{
  __shared__ float sb[4];
  const int r = blockIdx.x, t = threadIdx.x;
  const int ind = indw[r] & (NE - 1);
  float xv = xn[(size_t)r * EDIM + t];
  float ev = embed[(size_t)ind * EDIM + t];
  float df = ev - xv;
  float s = df * df;
#pragma unroll
  for (int off = 32; off >= 1; off >>= 1) s += __shfl_xor(s, off);
  if ((t & 63) == 0) sb[t >> 6] = s;
  __syncthreads();
  if (t == 0) atomicAdd(scal + 2, sb[0] + sb[1] + sb[2] + sb[3]);
  atomicAdd(esum + (size_t)ind * EDIM + t, xv);
}

// ---------------------------------------------------------------------------
__global__ __launch_bounds__(256) void scalars_kernel(
    const float* __restrict__ ap, const float* __restrict__ scal, float* __restrict__ out)
{
  __shared__ float sb[4];
  const int t = threadIdx.x;
  float h = 0.f;
  for (int c = t; c < NE; c += 256) {
    float apv = ap[c] * (1.0f / NROWS);
    h -= apv * logf(apv);
  }
#pragma unroll
  for (int off = 32; off >= 1; off >>= 1) h += __shfl_xor(h, off);
  if ((t & 63) == 0) sb[t >> 6] = h;
  __syncthreads();
  if (t == 0) {
    float Hmax = sb[0] + sb[1] + sb[2] + sb[3];
    float commit = scal[2] * (1.0f / ((float)NROWS * (float)EDIM));
    float emin = scal[1] * (1.0f / (float)NROWS);
    out[OFF_LOSS] = commit - Hmax;
    out[OFF_EMIN] = emin;
    out[OFF_CMT]  = commit;
  }
}

// ---------------------------------------------------------------------------
__global__ __launch_bounds__(256) void cluster_kernel(
    const float* __restrict__ cs_in, const float* __restrict__ bins,
    float* __restrict__ cn, float* __restrict__ scal)
{
  __shared__ float sb[4];
  const int c = blockIdx.x * 256 + threadIdx.x;
  const int t = threadIdx.x;
  float v = cs_in[c] * 0.99f + bins[c] * 0.01f;
  cn[c] = v;
  float s = v;
#pragma unroll
  for (int off = 32; off >= 1; off >>= 1) s += __shfl_xor(s, off);
  if ((t & 63) == 0) sb[t >> 6] = s;
  __syncthreads();
  if (t == 0) atomicAdd(scal + 0, sb[0] + sb[1] + sb[2] + sb[3]);
}

// ---------------------------------------------------------------------------
__global__ __launch_bounds__(256) void scan_kernel(
    const float* __restrict__ cn, const float* __restrict__ scal,
    int* __restrict__ idxs, float* __restrict__ csm, float* __restrict__ out)
{
  __shared__ int ssum[256];
  const int t = threadIdx.x;
  const int base = t * 32;
  int cnt = 0;
  for (int j = 0; j < 32; ++j) cnt += (cn[base + j] < 0.1f) ? 1 : 0;
  ssum[t] = cnt;
  __syncthreads();
  for (int off = 1; off < 256; off <<= 1) {
    int v = (t >= off) ? ssum[t - off] : 0;
    __syncthreads();
    ssum[t] += v;
    __syncthreads();
  }
  int run = (t > 0) ? ssum[t - 1] : 0;
  const float total = scal[0];
  const float dscale = total / (total + (float)NE * 1e-5f);
  for (int j = 0; j < 32; ++j) {
    float v = cn[base + j];
    bool ex = v < 0.1f;                 // DEAD_THRESH * RATIO
    run += ex ? 1 : 0;
    int idx = run - 1; if (idx < 0) idx = 0;
    idx &= (NROWS - 1);
    idxs[base + j] = idx;
    csm[base + j] = (v + 1e-5f) * dscale;
    out[OFF_CSF + base + j] = ex ? 0.12f : v;   // RESET_CS*RATIO
  }
}

// ---------------------------------------------------------------------------
__global__ __launch_bounds__(256) void embed_out_kernel(
    const float* __restrict__ cn, const float* __restrict__ csm,
    const int* __restrict__ idxs, const float* __restrict__ xn,
    const float* __restrict__ embed_avg, const float* __restrict__ esum,
    float* __restrict__ out)
{
  const int c = blockIdx.x, t = threadIdx.x;
  float oe, oa;
  if (cn[c] < 0.1f) {
    float s = xn[(size_t)(idxs[c] & (NROWS - 1)) * EDIM + t];
    oe = s; oa = s * 0.12f;
  } else {
    float an = embed_avg[(size_t)c * EDIM + t] * 0.99f
             + esum[(size_t)c * EDIM + t] * 0.01f;
    oa = an; oe = an / csm[c];
  }
  out[OFF_EMB  + (size_t)c * EDIM + t] = oe;
  out[OFF_EAVG + (size_t)c * EDIM + t] = oa;
}

// ---------------------------------------------------------------------------
extern "C" void kernel_launch(void* const* d_in, const int* in_sizes, int n_in,
                              void* d_out, int out_size, void* d_ws, size_t ws_size,
                              hipStream_t stream)
{
  const float* x         = (const float*)d_in[0];
  const float* W_in      = (const float*)d_in[1];
  const float* b_in      = (const float*)d_in[2];
  const float* W_out     = (const float*)d_in[3];
  const float* b_out     = (const float*)d_in[4];
  const float* embed     = (const float*)d_in[5];
  const float* embed_avg = (const float*)d_in[6];
  const float* cs_in     = (const float*)d_in[7];
  float* out = (float*)d_out;
  char* ws = (char*)d_ws;

  if (ws_size < (size_t)W_END) {   // guard (R6 proved it doesn't fire)
    zero_out_kernel<<<(out_size + 255) / 256, 256, 0, stream>>>(out, out_size);
    return;
  }

  float* xn    = (float*)(ws + W_XN);
  float* esum  = (float*)(ws + W_ESUM);
  u64*   rowmin= (u64*)  (ws + W_RMIN);
  float* rowZ  = (float*)(ws + W_RZ);
  float* rowS1 = (float*)(ws + W_RS1);
  float* invZ  = (float*)(ws + W_INVZ);
  int*   indw  = (int*)  (ws + W_INDW);
  float* bins  = (float*)(ws + W_BINS);
  float* cn    = (float*)(ws + W_CN);
  float* csm   = (float*)(ws + W_CSM);
  int*   idxs  = (int*)  (ws + W_IDXS);
  float* ap    = (float*)(ws + W_AP);
  float* scal  = (float*)(ws + W_SCAL);

  hipMemsetAsync(ws + W_ESUM, 0,    W_RMIN - W_ESUM, stream); // esum = 0
  hipMemsetAsync(ws + W_RMIN, 0xFF, W_RZ - W_RMIN,   stream); // rowmin = ~0
  hipMemsetAsync(ws + W_RZ,   0,    W_END - W_RZ,    stream); // rest = 0

  // 1. x_proj = x @ W_in^T + b_in  (fp32 into ws)
  gemm_in_kernel<<<dim3(NROWS / 64, EDIM / 64), 256, 0, stream>>>(
      x, W_in, b_in, xn);
  // 2. l2norm in place
  l2norm_kernel<<<NROWS, 256, 0, stream>>>(xn);
  // 3. phase 1: argmin / Z / S1 (fp32, exact argmin)
  phase1_kernel<<<dim3(NROWS / 64, NE / P_CSPAN), 256, 0, stream>>>(
      xn, embed, rowmin, rowZ, rowS1);
  // 4. per-row finalize (ind, bins, invZ, entropy_to_min)
  row_finalize_kernel<<<NROWS / 256, 256, 0, stream>>>(
      rowmin, rowZ, rowS1, invZ, indw, bins, scal, out);
  // 5. z_q GEMM directly into d_out chunk 0 (fp32)
  gemm_out_kernel<<<dim3(NROWS / 64, ODIM / 64), 256, 0, stream>>>(
      embed, W_out, b_out, indw, out + OFF_ZQ);
  // 6. commit loss + embed_sum scatter
  scatter_commit_kernel<<<NROWS, 256, 0, stream>>>(xn, embed, indw, esum, scal);
  // 7. phase 2: ap accumulation via bf16x3 MFMA
  phase2_mfma_kernel<<<dim3(NROWS / 128, NE / 128), 256, 0, stream>>>(
      xn, embed, invZ, ap);
  // 8. scalar outputs
  scalars_kernel<<<1, 256, 0, stream>>>(ap, scal, out);
  // 9. cluster_new + total
  cluster_kernel<<<NE / 256, 256, 0, stream>>>(cs_in, bins, cn, scal);
  // 10. expiry scan + cluster_final
  scan_kernel<<<1, 256, 0, stream>>>(cn, scal, idxs, csm, out);
  // 11. embed_final / embed_avg_final
  embed_out_kernel<<<NE, 256, 0, stream>>>(cn, csm, idxs, xn, embed_avg, esum, out);
}

// Round 2
// 1381.261 us; speedup vs baseline: 1.9288x; 1.4193x over previous
//
#include <hip/hip_runtime.h>
#include <hip/hip_bf16.h>

typedef unsigned long long u64;
typedef __bf16 bf16_t;
typedef __attribute__((ext_vector_type(8))) __bf16 bf16x8;
typedef __attribute__((ext_vector_type(4))) __bf16 bf16x4;
typedef __attribute__((ext_vector_type(4))) float f32x4;

#define NROWS 16384
#define KLAT  768
#define EDIM  256
#define NE    8192
#define ODIM  768

// output element offsets (FLOAT32 elements — d_out is fp32, 16,801,795 elems)
#define OFF_ZQ   0
#define OFF_IND  12582912
#define OFF_LOSS 12599296
#define OFF_EMB  12599297
#define OFF_EAVG 14696449
#define OFF_CSF  16793601
#define OFF_EMIN 16801793
#define OFF_CMT  16801794

// workspace layout (~25.76 MB proven)
// W_XN now holds bf16 hi/lo planes of normalized xn (8 MB + 8 MB).
// W_ESUM holds bf16 hi/lo planes of embed (4+4 MB) until phase2, then esum.
#define W_XN    0u
#define W_ESUM  16777216u
#define W_RMIN  25165824u    // u64 rowmin [16384]
#define W_RZ    25296896u    // f32 rowZ
#define W_RS1   25362432u    // f32 rowS1
#define W_INVZ  25427968u    // f32 invZ
#define W_INDW  25493504u    // i32 ind
#define W_BINS  25559040u    // f32 bins [8192]
#define W_CN    25591808u    // f32 cluster_new
#define W_CSM   25624576u    // f32 cs smoothed
#define W_IDXS  25657344u    // i32 sampled idx
#define W_AP    25690112u    // f32 ap [8192]
#define W_SCAL  25722880u    // f32 scal[4]
#define W_END   25722896u

#define EPSC    1e-4f        // candidate threshold: ~5x bf16x3 error bound
#define CANDCAP 16

// ---------------------------------------------------------------------------
__global__ __launch_bounds__(256) void zero_out_kernel(float* __restrict__ out, int n)
{
  int i = blockIdx.x * 256 + threadIdx.x;
  if (i < n) out[i] = 0.0f;
}

// ---------------------------------------------------------------------------
// GEMM-in: x_proj[M][256] = x[M][768] @ W_in[256][768]^T + b_in
// (fp32, written into d_out z_q scratch region)
// ---------------------------------------------------------------------------
__global__ __launch_bounds__(256) void gemm_in_kernel(
    const float* __restrict__ A, const float* __restrict__ B,
    const float* __restrict__ bias, float* __restrict__ C)
{
  __shared__ float As[16][64];
  __shared__ float Bs[16][64];
  const int tid = threadIdx.x;
  const int tx = tid & 15, ty = tid >> 4;
  const int bm = blockIdx.x << 6, bn = blockIdx.y << 6;
  const int lr = tid >> 2, lk = (tid & 3) << 2;
  const size_t aoff = (size_t)(bm + lr) * KLAT;
  const size_t boff = (size_t)(bn + lr) * KLAT;
  float acc[4][4] = {};
  for (int k0 = 0; k0 < KLAT; k0 += 16) {
    __syncthreads();
    float4 av = *(const float4*)(A + aoff + k0 + lk);
    float4 bv = *(const float4*)(B + boff + k0 + lk);
    As[lk + 0][lr] = av.x; As[lk + 1][lr] = av.y; As[lk + 2][lr] = av.z; As[lk + 3][lr] = av.w;
    Bs[lk + 0][lr] = bv.x; Bs[lk + 1][lr] = bv.y; Bs[lk + 2][lr] = bv.z; Bs[lk + 3][lr] = bv.w;
    __syncthreads();
#pragma unroll
    for (int kk = 0; kk < 16; ++kk) {
      float4 a4 = *(const float4*)&As[kk][ty << 2];
      float4 b4 = *(const float4*)&Bs[kk][tx << 2];
      float ar[4] = {a4.x, a4.y, a4.z, a4.w};
      float br[4] = {b4.x, b4.y, b4.z, b4.w};
#pragma unroll
      for (int i = 0; i < 4; ++i)
#pragma unroll
        for (int j = 0; j < 4; ++j)
          acc[i][j] = fmaf(ar[i], br[j], acc[i][j]);
    }
  }
  float4 b4 = *(const float4*)(bias + bn + (tx << 2));
  float bb[4] = {b4.x, b4.y, b4.z, b4.w};
#pragma unroll
  for (int i = 0; i < 4; ++i) {
    const size_t row = (size_t)(bm + (ty << 2) + i);
    float4 o = make_float4(acc[i][0] + bb[0], acc[i][1] + bb[1],
                           acc[i][2] + bb[2], acc[i][3] + bb[3]);
    *(float4*)(C + row * EDIM + bn + (tx << 2)) = o;
  }
}

// ---------------------------------------------------------------------------
// GEMM-out: out[M][768] = embed[ind[M]][256] @ W_out[768][256]^T + b_out
// Runs LAST (overwrites the z_q scratch region).
// ---------------------------------------------------------------------------
__global__ __launch_bounds__(256) void gemm_out_kernel(
    const float* __restrict__ A, const float* __restrict__ B,
    const float* __restrict__ bias, const int* __restrict__ gather,
    float* __restrict__ C)
{
  __shared__ float As[16][64];
  __shared__ float Bs[16][64];
  const int tid = threadIdx.x;
  const int tx = tid & 15, ty = tid >> 4;
  const int bm = blockIdx.x << 6, bn = blockIdx.y << 6;
  const int lr = tid >> 2, lk = (tid & 3) << 2;
  const size_t arow = (size_t)(gather[bm + lr] & (NE - 1));
  const size_t aoff = arow * EDIM;
  const size_t boff = (size_t)(bn + lr) * EDIM;
  float acc[4][4] = {};
  for (int k0 = 0; k0 < EDIM; k0 += 16) {
    __syncthreads();
    float4 av = *(const float4*)(A + aoff + k0 + lk);
    float4 bv = *(const float4*)(B + boff + k0 + lk);
    As[lk + 0][lr] = av.x; As[lk + 1][lr] = av.y; As[lk + 2][lr] = av.z; As[lk + 3][lr] = av.w;
    Bs[lk + 0][lr] = bv.x; Bs[lk + 1][lr] = bv.y; Bs[lk + 2][lr] = bv.z; Bs[lk + 3][lr] = bv.w;
    __syncthreads();
#pragma unroll
    for (int kk = 0; kk < 16; ++kk) {
      float4 a4 = *(const float4*)&As[kk][ty << 2];
      float4 b4 = *(const float4*)&Bs[kk][tx << 2];
      float ar[4] = {a4.x, a4.y, a4.z, a4.w};
      float br[4] = {b4.x, b4.y, b4.z, b4.w};
#pragma unroll
      for (int i = 0; i < 4; ++i)
#pragma unroll
        for (int j = 0; j < 4; ++j)
          acc[i][j] = fmaf(ar[i], br[j], acc[i][j]);
    }
  }
  float4 b4 = *(const float4*)(bias + bn + (tx << 2));
  float bb[4] = {b4.x, b4.y, b4.z, b4.w};
#pragma unroll
  for (int i = 0; i < 4; ++i) {
    const size_t row = (size_t)(bm + (ty << 2) + i);
    float4 o = make_float4(acc[i][0] + bb[0], acc[i][1] + bb[1],
                           acc[i][2] + bb[2], acc[i][3] + bb[3]);
    *(float4*)(C + row * ODIM + bn + (tx << 2)) = o;
  }
}

// ---------------------------------------------------------------------------
// l2norm in place (fp32 in d_out scratch) + write bf16 hi/lo planes
// ---------------------------------------------------------------------------
__global__ __launch_bounds__(256) void l2norm_split_kernel(
    float* __restrict__ xnf, bf16_t* __restrict__ xh, bf16_t* __restrict__ xl)
{
  __shared__ float sb[4];
  const int r = blockIdx.x, t = threadIdx.x;
  const size_t o = (size_t)r * EDIM + t;
  float v = xnf[o];
  float s = v * v;
#pragma unroll
  for (int off = 32; off >= 1; off >>= 1) s += __shfl_xor(s, off);
  if ((t & 63) == 0) sb[t >> 6] = s;
  __syncthreads();
  float tot = sb[0] + sb[1] + sb[2] + sb[3];
  float nv = v / sqrtf(tot);
  xnf[o] = nv;
  bf16_t h = (bf16_t)nv;
  xh[o] = h;
  xl[o] = (bf16_t)(nv - (float)h);
}

// ---------------------------------------------------------------------------
__global__ __launch_bounds__(256) void embed_split_kernel(
    const float* __restrict__ embed, bf16_t* __restrict__ eh, bf16_t* __restrict__ el)
{
  const int i = (blockIdx.x * 256 + threadIdx.x) << 2;
  float4 v = *(const float4*)(embed + i);
  bf16_t h0 = (bf16_t)v.x, h1 = (bf16_t)v.y, h2 = (bf16_t)v.z, h3 = (bf16_t)v.w;
  bf16x4 hv = {h0, h1, h2, h3};
  bf16x4 lv = {(bf16_t)(v.x - (float)h0), (bf16_t)(v.y - (float)h1),
               (bf16_t)(v.z - (float)h2), (bf16_t)(v.w - (float)h3)};
  *(bf16x4*)(eh + i) = hv;
  *(bf16x4*)(el + i) = lv;
}

// ---------------------------------------------------------------------------
// Phase 1 (MFMA bf16x3): d~ = xn·embed; per-row approx argmin key + Z + S1.
// Tile 128x128, full K=256 per block, 4 waves 2x2, 4x4 frags of 16x16x32.
// Staging = pure 16B vector copies from precomputed planes.
// ---------------------------------------------------------------------------
__global__ __launch_bounds__(256) void phase1_mfma_kernel(
    const bf16_t* __restrict__ xh, const bf16_t* __restrict__ xl,
    const bf16_t* __restrict__ eh, const bf16_t* __restrict__ el,
    u64* __restrict__ rowmin, float* __restrict__ rowZ, float* __restrict__ rowS1)
{
  __shared__ bf16_t Ah[128][72];
  __shared__ bf16_t Al[128][72];
  __shared__ bf16_t Bh[128][72];
  __shared__ bf16_t Bl[128][72];
  const int tid  = threadIdx.x;
  const int lane = tid & 63;
  const int wave = tid >> 6;
  const int wm = wave >> 1, wn = wave & 1;
  const int row_m = blockIdx.x << 7;
  const int col_n = blockIdx.y << 7;
  const int srow = tid >> 3;          // 0..31
  const int sk   = (tid & 7) << 3;    // 0..56

  f32x4 acc[4][4] = {};

  for (int k0 = 0; k0 < EDIM; k0 += 64) {
    __syncthreads();
#pragma unroll
    for (int p = 0; p < 4; ++p) {
      const int r = srow + (p << 5);
      const size_t ga = (size_t)(row_m + r) * EDIM + k0 + sk;
      const size_t gb = (size_t)(col_n + r) * EDIM + k0 + sk;
      *(bf16x8*)&Ah[r][sk] = *(const bf16x8*)(xh + ga);
      *(bf16x8*)&Al[r][sk] = *(const bf16x8*)(xl + ga);
      *(bf16x8*)&Bh[r][sk] = *(const bf16x8*)(eh + gb);
      *(bf16x8*)&Bl[r][sk] = *(const bf16x8*)(el + gb);
    }
    __syncthreads();
#pragma unroll
    for (int kk = 0; kk < 2; ++kk) {
      const int kf = (kk << 5) + ((lane >> 4) << 3);
      bf16x8 ah[4], alr[4], bh[4], blr[4];
#pragma unroll
      for (int m = 0; m < 4; ++m) {
        const int r = (wm << 6) + (m << 4) + (lane & 15);
        ah[m]  = *(const bf16x8*)&Ah[r][kf];
        alr[m] = *(const bf16x8*)&Al[r][kf];
      }
#pragma unroll
      for (int n = 0; n < 4; ++n) {
        const int c = (wn << 6) + (n << 4) + (lane & 15);
        bh[n]  = *(const bf16x8*)&Bh[c][kf];
        blr[n] = *(const bf16x8*)&Bl[c][kf];
      }
#pragma unroll
      for (int m = 0; m < 4; ++m)
#pragma unroll
        for (int n = 0; n < 4; ++n) {
          acc[m][n] = __builtin_amdgcn_mfma_f32_16x16x32_bf16(ah[m],  bh[n],  acc[m][n], 0, 0, 0);
          acc[m][n] = __builtin_amdgcn_mfma_f32_16x16x32_bf16(ah[m],  blr[n], acc[m][n], 0, 0, 0);
          acc[m][n] = __builtin_amdgcn_mfma_f32_16x16x32_bf16(alr[m], bh[n],  acc[m][n], 0, 0, 0);
        }
    }
  }

  // epilogue: C/D layout col = lane&15, row = (lane>>4)*4 + q
  const int colb = col_n + (wn << 6) + (lane & 15);
#pragma unroll
  for (int m = 0; m < 4; ++m) {
#pragma unroll
    for (int q = 0; q < 4; ++q) {
      float Z = 0.f, S1 = 0.f;
      u64 mk = ~0ull;
#pragma unroll
      for (int n = 0; n < 4; ++n) {
        float d = acc[m][n][q];
        float l = 10.f * d;
        float e = __expf(l);
        Z += e; S1 += l * e;
        u64 key = ((u64)__float_as_uint(d + 2.0f) << 32) | (unsigned)(colb + (n << 4));
        if (key < mk) mk = key;
      }
#pragma unroll
      for (int off = 1; off < 16; off <<= 1) {
        u64 ok = __shfl_xor(mk, off);
        if (ok < mk) mk = ok;
        Z  += __shfl_xor(Z, off);
        S1 += __shfl_xor(S1, off);
      }
      if ((lane & 15) == 0) {
        const int row = row_m + (wm << 6) + (m << 4) + ((lane >> 4) << 2) + q;
        atomicMin(rowmin + row, mk);
        atomicAdd(rowZ + row, Z);
        atomicAdd(rowS1 + row, S1);
      }
    }
  }
}

// ---------------------------------------------------------------------------
// Phase 2 (MFMA bf16x3, bit-identical d~ to phase1): ap accumulation +
// candidate collection (d~ <= d~min + EPSC) for exact argmin repair.
// ---------------------------------------------------------------------------
__global__ __launch_bounds__(256) void phase2_mfma_kernel(
    const bf16_t* __restrict__ xh, const bf16_t* __restrict__ xl,
    const bf16_t* __restrict__ eh, const bf16_t* __restrict__ el,
    const float* __restrict__ invZ, const u64* __restrict__ rowmin,
    float* __restrict__ ap, int* __restrict__ ccnt, int* __restrict__ clist)
{
  __shared__ bf16_t Ah[128][72];
  __shared__ bf16_t Al[128][72];
  __shared__ bf16_t Bh[128][72];
  __shared__ bf16_t Bl[128][72];
  const int tid  = threadIdx.x;
  const int lane = tid & 63;
  const int wave = tid >> 6;
  const int wm = wave >> 1, wn = wave & 1;
  const int row_m = blockIdx.x << 7;
  const int col_n = blockIdx.y << 7;
  const int srow = tid >> 3;
  const int sk   = (tid & 7) << 3;

  f32x4 acc[4][4] = {};

  for (int k0 = 0; k0 < EDIM; k0 += 64) {
    __syncthreads();
#pragma unroll
    for (int p = 0; p < 4; ++p) {
      const int r = srow + (p << 5);
      const size_t ga = (size_t)(row_m + r) * EDIM + k0 + sk;
      const size_t gb = (size_t)(col_n + r) * EDIM + k0 + sk;
      *(bf16x8*)&Ah[r][sk] = *(const bf16x8*)(xh + ga);
      *(bf16x8*)&Al[r][sk] = *(const bf16x8*)(xl + ga);
      *(bf16x8*)&Bh[r][sk] = *(const bf16x8*)(eh + gb);
      *(bf16x8*)&Bl[r][sk] = *(const bf16x8*)(el + gb);
    }
    __syncthreads();
#pragma unroll
    for (int kk = 0; kk < 2; ++kk) {
      const int kf = (kk << 5) + ((lane >> 4) << 3);
      bf16x8 ah[4], alr[4], bh[4], blr[4];
#pragma unroll
      for (int m = 0; m < 4; ++m) {
        const int r = (wm << 6) + (m << 4) + (lane & 15);
        ah[m]  = *(const bf16x8*)&Ah[r][kf];
        alr[m] = *(const bf16x8*)&Al[r][kf];
      }
#pragma unroll
      for (int n = 0; n < 4; ++n) {
        const int c = (wn << 6) + (n << 4) + (lane & 15);
        bh[n]  = *(const bf16x8*)&Bh[c][kf];
        blr[n] = *(const bf16x8*)&Bl[c][kf];
      }
#pragma unroll
      for (int m = 0; m < 4; ++m)
#pragma unroll
        for (int n = 0; n < 4; ++n) {
          acc[m][n] = __builtin_amdgcn_mfma_f32_16x16x32_bf16(ah[m],  bh[n],  acc[m][n], 0, 0, 0);
          acc[m][n] = __builtin_amdgcn_mfma_f32_16x16x32_bf16(ah[m],  blr[n], acc[m][n], 0, 0, 0);
          acc[m][n] = __builtin_amdgcn_mfma_f32_16x16x32_bf16(alr[m], bh[n],  acc[m][n], 0, 0, 0);
        }
    }
  }

  float iz[4][4], dmn[4][4];
  int rowv[4][4];
#pragma unroll
  for (int m = 0; m < 4; ++m)
#pragma unroll
    for (int q = 0; q < 4; ++q) {
      const int row = row_m + (wm << 6) + (m << 4) + ((lane >> 4) << 2) + q;
      rowv[m][q] = row;
      iz[m][q]  = invZ[row];
      dmn[m][q] = __uint_as_float((unsigned)(rowmin[row] >> 32)) - 2.0f + EPSC;
    }
  const int colb = col_n + (wn << 6) + (lane & 15);
#pragma unroll
  for (int n = 0; n < 4; ++n) {
    float s = 0.f;
#pragma unroll
    for (int m = 0; m < 4; ++m)
#pragma unroll
      for (int q = 0; q < 4; ++q) {
        float d = acc[m][n][q];
        s += __expf(10.f * d) * iz[m][q];
        if (d <= dmn[m][q]) {
          int pos = atomicAdd(ccnt + rowv[m][q], 1);
          if (pos < CANDCAP) clist[(rowv[m][q] << 4) + pos] = colb + (n << 4);
        }
      }
    s += __shfl_xor(s, 16);
    s += __shfl_xor(s, 32);
    if (lane < 16)
      atomicAdd(ap + col_n + (wn << 6) + (n << 4) + lane, s);
  }
}

// ---------------------------------------------------------------------------
// Repair: exact fp32 argmin over the candidate set (approx-best + list).
// 4 threads per row; lexicographic (d, idx) min == jnp.argmin semantics.
// ---------------------------------------------------------------------------
__global__ __launch_bounds__(256) void repair_kernel(
    const float* __restrict__ xnf, const float* __restrict__ embed,
    const u64* __restrict__ rowmin, const int* __restrict__ ccnt,
    const int* __restrict__ clist, int* __restrict__ indw,
    float* __restrict__ bins, float* __restrict__ out)
{
  const int t = threadIdx.x;
  const int row = blockIdx.x * 64 + (t >> 2);
  const int sub = t & 3;
  const int base = ((int)(unsigned)(rowmin[row] & 0xFFFFFFFFull)) & (NE - 1);
  int cnt = ccnt[row];
  if (cnt > CANDCAP) cnt = CANDCAP;
  float bestD = 1e30f;
  int bestI = NE;
  const float* xr = xnf + (size_t)row * EDIM + (sub << 6);
  for (int j = -1; j < cnt; ++j) {
    const int c = (j < 0) ? base : (clist[(row << 4) + j] & (NE - 1));
    const float* er = embed + (size_t)c * EDIM + (sub << 6);
    float s = 0.f;
#pragma unroll
    for (int k = 0; k < 64; k += 4) {
      float4 a = *(const float4*)(xr + k);
      float4 b = *(const float4*)(er + k);
      s = fmaf(a.x, b.x, s); s = fmaf(a.y, b.y, s);
      s = fmaf(a.z, b.z, s); s = fmaf(a.w, b.w, s);
    }
    s += __shfl_xor(s, 1);
    s += __shfl_xor(s, 2);
    if (s < bestD || (s == bestD && c < bestI)) { bestD = s; bestI = c; }
  }
  if (sub == 0) {
    indw[row] = bestI;
    out[OFF_IND + row] = (float)bestI;
    atomicAdd(bins + bestI, 1.0f);
  }
}

// ---------------------------------------------------------------------------
__global__ __launch_bounds__(256) void row_finalize_kernel(
    const float* __restrict__ rowZ, const float* __restrict__ rowS1,
    float* __restrict__ invZ, float* __restrict__ scal)
{
  __shared__ float sb[4];
  const int r = blockIdx.x * 256 + threadIdx.x;
  const int t = threadIdx.x;
  float Z = rowZ[r], S1 = rowS1[r];
  invZ[r] = 1.0f / Z;
  float ent = logf(Z) - S1 / Z;
#pragma unroll
  for (int off = 32; off >= 1; off >>= 1) ent += __shfl_xor(ent, off);
  if ((t & 63) == 0) sb[t >> 6] = ent;
  __syncthreads();
  if (t == 0) atomicAdd(scal + 1, sb[0] + sb[1] + sb[2] + sb[3]);
}

// ---------------------------------------------------------------------------
__global__ __launch_bounds__(256) void scatter_commit_kernel(
    const float* __restrict__ xn, const float* __restrict__ embed,
    const int* __restrict__ indw, float* __restrict__ esum, float* __restrict__ scal)
{
  __shared__ float sb[4];
  const int r = blockIdx.x, t = threadIdx.x;
  const int ind = indw[r] & (NE - 1);
  float xv = xn[(size_t)r * EDIM + t];
  float ev = embed[(size_t)ind * EDIM + t];
  float df = ev - xv;
  float s = df * df;
#pragma unroll
  for (int off = 32; off >= 1; off >>= 1) s += __shfl_xor(s, off);
  if ((t & 63) == 0) sb[t >> 6] = s;
  __syncthreads();
  if (t == 0) atomicAdd(scal + 2, sb[0] + sb[1] + sb[2] + sb[3]);
  atomicAdd(esum + (size_t)ind * EDIM + t, xv);
}

// ---------------------------------------------------------------------------
__global__ __launch_bounds__(256) void scalars_kernel(
    const float* __restrict__ ap, const float* __restrict__ scal, float* __restrict__ out)
{
  __shared__ float sb[4];
  const int t = threadIdx.x;
  float h = 0.f;
  for (int c = t; c < NE; c += 256) {
    float apv = ap[c] * (1.0f / NROWS);
    h -= apv * logf(apv);
  }
#pragma unroll
  for (int off = 32; off >= 1; off >>= 1) h += __shfl_xor(h, off);
  if ((t & 63) == 0) sb[t >> 6] = h;
  __syncthreads();
  if (t == 0) {
    float Hmax = sb[0] + sb[1] + sb[2] + sb[3];
    float commit = scal[2] * (1.0f / ((float)NROWS * (float)EDIM));
    float emin = scal[1] * (1.0f / (float)NROWS);
    out[OFF_LOSS] = commit - Hmax;
    out[OFF_EMIN] = emin;
    out[OFF_CMT]  = commit;
  }
}

// ---------------------------------------------------------------------------
__global__ __launch_bounds__(256) void cluster_kernel(
    const float* __restrict__ cs_in, const float* __restrict__ bins,
    float* __restrict__ cn, float* __restrict__ scal)
{
  __shared__ float sb[4];
  const int c = blockIdx.x * 256 + threadIdx.x;
  const int t = threadIdx.x;
  float v = cs_in[c] * 0.99f + bins[c] * 0.01f;
  cn[c] = v;
  float s = v;
#pragma unroll
  for (int off = 32; off >= 1; off >>= 1) s += __shfl_xor(s, off);
  if ((t & 63) == 0) sb[t >> 6] = s;
  __syncthreads();
  if (t == 0) atomicAdd(scal + 0, sb[0] + sb[1] + sb[2] + sb[3]);
}

// ---------------------------------------------------------------------------
__global__ __launch_bounds__(256) void scan_kernel(
    const float* __restrict__ cn, const float* __restrict__ scal,
    int* __restrict__ idxs, float* __restrict__ csm, float* __restrict__ out)
{
  __shared__ int ssum[256];
  const int t = threadIdx.x;
  const int base = t * 32;
  int cnt = 0;
  for (int j = 0; j < 32; ++j) cnt += (cn[base + j] < 0.1f) ? 1 : 0;
  ssum[t] = cnt;
  __syncthreads();
  for (int off = 1; off < 256; off <<= 1) {
    int v = (t >= off) ? ssum[t - off] : 0;
    __syncthreads();
    ssum[t] += v;
    __syncthreads();
  }
  int run = (t > 0) ? ssum[t - 1] : 0;
  const float total = scal[0];
  const float dscale = total / (total + (float)NE * 1e-5f);
  for (int j = 0; j < 32; ++j) {
    float v = cn[base + j];
    bool ex = v < 0.1f;                 // DEAD_THRESH * RATIO
    run += ex ? 1 : 0;
    int idx = run - 1; if (idx < 0) idx = 0;
    idx &= (NROWS - 1);
    idxs[base + j] = idx;
    csm[base + j] = (v + 1e-5f) * dscale;
    out[OFF_CSF + base + j] = ex ? 0.12f : v;   // RESET_CS*RATIO
  }
}

// ---------------------------------------------------------------------------
__global__ __launch_bounds__(256) void embed_out_kernel(
    const float* __restrict__ cn, const float* __restrict__ csm,
    const int* __restrict__ idxs, const float* __restrict__ xn,
    const float* __restrict__ embed_avg, const float* __restrict__ esum,
    float* __restrict__ out)
{
  const int c = blockIdx.x, t = threadIdx.x;
  float oe, oa;
  if (cn[c] < 0.1f) {
    float s = xn[(size_t)(idxs[c] & (NROWS - 1)) * EDIM + t];
    oe = s; oa = s * 0.12f;
  } else {
    float an = embed_avg[(size_t)c * EDIM + t] * 0.99f
             + esum[(size_t)c * EDIM + t] * 0.01f;
    oa = an; oe = an / csm[c];
  }
  out[OFF_EMB  + (size_t)c * EDIM + t] = oe;
  out[OFF_EAVG + (size_t)c * EDIM + t] = oa;
}

// ---------------------------------------------------------------------------
extern "C" void kernel_launch(void* const* d_in, const int* in_sizes, int n_in,
                              void* d_out, int out_size, void* d_ws, size_t ws_size,
                              hipStream_t stream)
{
  const float* x         = (const float*)d_in[0];
  const float* W_in      = (const float*)d_in[1];
  const float* b_in      = (const float*)d_in[2];
  const float* W_out     = (const float*)d_in[3];
  const float* b_out     = (const float*)d_in[4];
  const float* embed     = (const float*)d_in[5];
  const float* embed_avg = (const float*)d_in[6];
  const float* cs_in     = (const float*)d_in[7];
  float* out = (float*)d_out;
  char* ws = (char*)d_ws;

  if (ws_size < (size_t)W_END) {   // guard (proven not to fire)
    zero_out_kernel<<<(out_size + 255) / 256, 256, 0, stream>>>(out, out_size);
    return;
  }

  bf16_t* xh = (bf16_t*)(ws + W_XN);
  bf16_t* xl = (bf16_t*)(ws + W_XN + 8388608u);
  bf16_t* eh = (bf16_t*)(ws + W_ESUM);
  bf16_t* el = (bf16_t*)(ws + W_ESUM + 4194304u);
  float* esum  = (float*)(ws + W_ESUM);
  u64*   rowmin= (u64*)  (ws + W_RMIN);
  float* rowZ  = (float*)(ws + W_RZ);
  float* rowS1 = (float*)(ws + W_RS1);
  float* invZ  = (float*)(ws + W_INVZ);
  int*   indw  = (int*)  (ws + W_INDW);
  float* bins  = (float*)(ws + W_BINS);
  float* cn    = (float*)(ws + W_CN);
  float* csm   = (float*)(ws + W_CSM);
  int*   idxs  = (int*)  (ws + W_IDXS);
  float* ap    = (float*)(ws + W_AP);
  float* scal  = (float*)(ws + W_SCAL);

  // d_out z_q region (48 MB) as scratch until gemm_out (which runs last):
  //   [0, 16MB)      : fp32 normalized xn [16384][256]
  //   +4194304 elems : i32 ccnt [16384]
  //   then           : i32 clist [16384][16]
  float* xnf  = out + OFF_ZQ;
  int* ccnt   = (int*)(out + OFF_ZQ + 4194304);
  int* clist  = ccnt + NROWS;

  hipMemsetAsync(ws + W_RMIN, 0xFF, W_RZ - W_RMIN, stream); // rowmin = ~0
  hipMemsetAsync(ws + W_RZ,   0,    W_END - W_RZ,  stream); // rest = 0
  hipMemsetAsync(ccnt, 0, NROWS * sizeof(int), stream);     // candidate counts

  // 1. x_proj = x @ W_in^T + b_in  (fp32 into d_out scratch)
  gemm_in_kernel<<<dim3(NROWS / 64, EDIM / 64), 256, 0, stream>>>(
      x, W_in, b_in, xnf);
  // 2. l2norm in place + bf16 hi/lo planes
  l2norm_split_kernel<<<NROWS, 256, 0, stream>>>(xnf, xh, xl);
  // 3. embed bf16 hi/lo planes (into esum region, freed after phase2)
  embed_split_kernel<<<(NE * EDIM / 4) / 256, 256, 0, stream>>>(embed, eh, el);
  // 4. phase 1: approx argmin key / Z / S1 via bf16x3 MFMA
  phase1_mfma_kernel<<<dim3(NROWS / 128, NE / 128), 256, 0, stream>>>(
      xh, xl, eh, el, rowmin, rowZ, rowS1);
  // 5. per-row invZ + entropy_to_min
  row_finalize_kernel<<<NROWS / 256, 256, 0, stream>>>(rowZ, rowS1, invZ, scal);
  // 6. phase 2: ap accumulation + candidate collection (bit-identical d~)
  phase2_mfma_kernel<<<dim3(NROWS / 128, NE / 128), 256, 0, stream>>>(
      xh, xl, eh, el, invZ, rowmin, ap, ccnt, clist);
  // 7. free eh/el -> esum = 0
  hipMemsetAsync(ws + W_ESUM, 0, W_RMIN - W_ESUM, stream);
  // 8. exact argmin repair (fp32 dots over candidates) -> ind, bins
  repair_kernel<<<NROWS / 64, 256, 0, stream>>>(
      xnf, embed, rowmin, ccnt, clist, indw, bins, out);
  // 9. commit loss + embed_sum scatter
  scatter_commit_kernel<<<NROWS, 256, 0, stream>>>(xnf, embed, indw, esum, scal);
  // 10. cluster_new + total
  cluster_kernel<<<NE / 256, 256, 0, stream>>>(cs_in, bins, cn, scal);
  // 11. expiry scan + cluster_final
  scan_kernel<<<1, 256, 0, stream>>>(cn, scal, idxs, csm, out);
  // 12. scalar outputs
  scalars_kernel<<<1, 256, 0, stream>>>(ap, scal, out);
  // 13. embed_final / embed_avg_final (reads fp32 xn scratch)
  embed_out_kernel<<<NE, 256, 0, stream>>>(cn, csm, idxs, xnf, embed_avg, esum, out);
  // 14. z_q GEMM LAST (overwrites the z_q scratch region)
  gemm_out_kernel<<<dim3(NROWS / 64, ODIM / 64), 256, 0, stream>>>(
      embed, W_out, b_out, indw, out + OFF_ZQ);
}